// Round 1
// 6188.306 us; speedup vs baseline: 1.2929x; 1.2929x over previous
//
#include <hip/hip_runtime.h>
#include <hip/hip_bf16.h>
#include <math.h>

#define T_ 128
#define B_ 256
#define BP 512     // 2B (party batch)
#define D_ 1024
#define H_ 150
#define G_ 600     // 4H
#define O_ 300     // 2H
#define ROWS 16    // batch rows per scan block (one MFMA M-tile)
#define NT_ 38     // n-tiles of 16 covering 600 (608)
#define KT_ 5      // k-tiles of 32 covering 150 (160)
#define HSTR 168   // h hi/lo plane row stride in ushorts (16B-aligned, 2-way-free b128 frag reads)
#define GST 620    // gs row stride in floats (620%32=12 -> <=2-way on acc scatter)
#define TPB 512    // scan threads per block (8 waves)
#define EIT 5      // update-phase elems/thread: 16*160/512

typedef float v4f    __attribute__((ext_vector_type(4)));
typedef short bf16x8 __attribute__((ext_vector_type(8)));
typedef float f32x4  __attribute__((ext_vector_type(4)));

// ---------------- workspace layout (4-byte words) ----------------
static const size_t INV_OFF   = 0;                                   // int[128*512]
static const size_t WIHT0_OFF = 65536;                               // 4 x 1024*600
static const size_t WIHT1_OFF = WIHT0_OFF + 4ull * 1024 * 600;       // 4 x 300*600
static const size_t WPK_OFF   = WIHT1_OFF + 4ull * 300 * 600;        // 8 combos x NT*KT*2*512 bf16
static const size_t WPK_WORDS = 8ull * NT_ * KT_ * 2 * 512 / 2;      // shorts/2 = 778,240 words
static const size_t XW_OFF    = WPK_OFF + WPK_WORDS;
static const size_t XSLOT     = 32768ull * 600;

static size_t hrnn_off(int nslots) { return XW_OFF + (size_t)nslots * XSLOT; }
static size_t hpr_off(int nslots)  { return hrnn_off(nslots) + 32768ull * 300; }
static size_t total_words(int nslots) { return hpr_off(nslots) + 65536ull * 300; }

// 6-slot (merged layer-1 scan) tier
static size_t hrnn_off6() { return XW_OFF + 6ull * XSLOT; }
static size_t hpr_off6()  { return hrnn_off6() + 32768ull * 300; }
static size_t total_words6() { return hpr_off6() + 65536ull * 300; }

// ---------------- fast transcendentals ----------------
__device__ __forceinline__ float fsig(float x) {
    return __builtin_amdgcn_rcpf(1.f + __expf(-x));
}
__device__ __forceinline__ float ftanh(float x) {
    float xc = fminf(fmaxf(x, -15.f), 15.f);
    float e = __expf(-2.f * xc);
    return (1.f - e) * __builtin_amdgcn_rcpf(1.f + e);
}

// ---------------- inverse map: (pos p, party row) -> dialogue row or -1 ----------
__global__ void k_pos(const int* __restrict__ qmask, int* __restrict__ inv) {
    int b = threadIdx.x;
    for (int p = 0; p < T_; ++p) {
        inv[p * BP + b] = -1;
        inv[p * BP + B_ + b] = -1;
    }
    int c0 = 0, c1 = 0;
    for (int t = 0; t < T_; ++t) {
        int s = qmask[(t * B_ + b) * 2 + 1];
        int p = s ? c1++ : c0++;
        inv[p * BP + s * B_ + b] = t * B_ + b;
    }
}

// ---------------- transpose W[g][k] -> WT[k][g] (for GEMM B^T) ----------------
__global__ void k_transpose(const float* __restrict__ src, float* __restrict__ dst,
                            int K) {
    int idx = blockIdx.x * 256 + threadIdx.x;
    int total = K * G_;
    if (idx < total) {
        int k = idx / G_, g = idx - k * G_;
        dst[idx] = src[(size_t)g * K + k];
    }
}

// ---------------- pack Whh[600][150] into MFMA B-fragment layout, split hi/lo ----
// layout: [combo][nt][kt][which(hi/lo)][lane][8]
struct PackArgs { const float* whh[8]; };
__global__ void k_pack(PackArgs pa, unsigned short* __restrict__ wpk) {
    int gid = blockIdx.x * 256 + threadIdx.x;
    int lane = gid & 63;
    int q = gid >> 6;
    int kt = q % KT_; q /= KT_;
    int nt = q % NT_; q /= NT_;
    if (q >= 8) return;
    const float* W = pa.whh[q];     // [600][150] row-major (gate-col major)
    int col = nt * 16 + (lane & 15);
    int kbase = kt * 32 + (lane >> 4) * 8;
    size_t base = ((((size_t)q * NT_ + nt) * KT_ + kt) * 2) * 512 + (size_t)lane * 8;
    for (int j = 0; j < 8; ++j) {
        int k = kbase + j;
        float v = (col < G_ && k < H_) ? W[(size_t)col * H_ + k] : 0.f;
        unsigned u = __float_as_uint(v);
        unsigned short hi = (unsigned short)(u >> 16);
        float hf = __uint_as_float(u & 0xffff0000u);
        unsigned short lo = (unsigned short)(__float_as_uint(v - hf) >> 16);
        wpk[base + j] = hi;
        wpk[base + 512 + j] = lo;
    }
}

// ---------------- fp32 GEMM: C[M,600] = A[M,K] @ BT[K,600] + bias ----------------
__global__ __launch_bounds__(256) void k_gemm(const float* __restrict__ A,
                                              const float* __restrict__ BT,
                                              const float* __restrict__ bias,
                                              float* __restrict__ C,
                                              int M, int K) {
    __shared__ __align__(16) float As[16][136];
    __shared__ __align__(16) float Bs[16][68];
    int n0 = blockIdx.x * 64, m0 = blockIdx.y * 128;
    int tid = threadIdx.x;
    int tx = tid & 15, ty = tid >> 4;
    int ar = tid >> 2, ac = (tid & 3) * 4;
    int kr = tid >> 4, nc = (tid & 15) * 4;
    float acc[8][4];
#pragma unroll
    for (int i = 0; i < 8; ++i)
#pragma unroll
        for (int j = 0; j < 4; ++j) acc[i][j] = 0.f;

    for (int k0 = 0; k0 < K; k0 += 16) {
        bool fullK = (k0 + 16 <= K);
#pragma unroll
        for (int half = 0; half < 2; ++half) {
            int m = m0 + ar + half * 64;
            const float* ap = A + (size_t)m * K + k0 + ac;
            if (fullK) {
                v4f v = *(const v4f*)ap;
                As[ac + 0][ar + half * 64] = v.x;
                As[ac + 1][ar + half * 64] = v.y;
                As[ac + 2][ar + half * 64] = v.z;
                As[ac + 3][ar + half * 64] = v.w;
            } else {
#pragma unroll
                for (int i = 0; i < 4; ++i) {
                    int k = k0 + ac + i;
                    As[ac + i][ar + half * 64] = (k < K) ? ap[i] : 0.f;
                }
            }
        }
        {
            int k = k0 + kr, n = n0 + nc;
            if (fullK && n + 3 < G_) {
                v4f v = *(const v4f*)(BT + (size_t)k * G_ + n);
                Bs[kr][nc + 0] = v.x; Bs[kr][nc + 1] = v.y;
                Bs[kr][nc + 2] = v.z; Bs[kr][nc + 3] = v.w;
            } else {
#pragma unroll
                for (int i = 0; i < 4; ++i) {
                    int nn = n + i;
                    Bs[kr][nc + i] = (k < K && nn < G_) ? BT[(size_t)k * G_ + nn] : 0.f;
                }
            }
        }
        __syncthreads();
#pragma unroll
        for (int kk = 0; kk < 16; ++kk) {
            v4f a0 = *(const v4f*)&As[kk][ty * 8];
            v4f a1 = *(const v4f*)&As[kk][ty * 8 + 4];
            v4f b  = *(const v4f*)&Bs[kk][tx * 4];
            const float* af = (const float*)&a0;
            const float* af2 = (const float*)&a1;
            const float* bf = (const float*)&b;
#pragma unroll
            for (int i = 0; i < 4; ++i)
#pragma unroll
                for (int j = 0; j < 4; ++j) {
                    acc[i][j] += af[i] * bf[j];
                    acc[4 + i][j] += af2[i] * bf[j];
                }
        }
        __syncthreads();
    }
    int n = n0 + tx * 4;
    if (n + 3 < G_) {
        v4f bv = *(const v4f*)(bias + n);
#pragma unroll
        for (int i = 0; i < 8; ++i) {
            int m = m0 + ty * 8 + i;
            v4f o = {acc[i][0] + bv.x, acc[i][1] + bv.y, acc[i][2] + bv.z, acc[i][3] + bv.w};
            *(v4f*)(C + (size_t)m * G_ + n) = o;
        }
    } else {
#pragma unroll
        for (int i = 0; i < 8; ++i) {
            int m = m0 + ty * 8 + i;
#pragma unroll
            for (int j = 0; j < 4; ++j)
                if (n + j < G_) C[(size_t)m * G_ + n + j] = acc[i][j] + bias[n + j];
        }
    }
}

// ---------------- MFMA LSTM scan: 16 rows/block, 8 waves, split-bf16 fp32 --------
// h kept in LDS as pre-split bf16 hi/lo planes in A-fragment-friendly layout:
// fragment read for lane l, kt: hsh[(l&15)*HSTR + kt*32 + (l>>4)*8 .. +8] (b128).
struct Combo {
    const float* xw;
    const unsigned short* wpk;   // packed B fragments [NT][KT][2][64][8]
    const float* bias;           // gatherIn padding fallback
    float* out;
    int Bn, colOff, bwd, gIn, gOut;
};
struct ScanArgs {
    Combo c[4];
    const int* inv;
    const float* addSrc;
    const float* umask;
    int blkStart[5];
};

__global__ __launch_bounds__(TPB) void k_scan(ScanArgs args) {
    int bx = blockIdx.x, ci = 0;
#pragma unroll
    for (int i = 1; i < 4; ++i)
        if (bx >= args.blkStart[i]) ci = i;
    Combo cb = args.c[ci];
    int row0 = (bx - args.blkStart[ci]) * ROWS;

    __shared__ __align__(16) unsigned short hsh[ROWS * HSTR];
    __shared__ __align__(16) unsigned short hsl[ROWS * HSTR];
    __shared__ float cs[ROWS * 152];
    __shared__ float gs[ROWS * GST];
    int tid = threadIdx.x;
    int lane = tid & 63, wv = tid >> 6;
    int col16 = lane & 15, quad = lane >> 4;
    for (int i = tid; i < ROWS * HSTR; i += TPB) { hsh[i] = 0; hsl[i] = 0; }
    for (int i = tid; i < ROWS * 152; i += TPB) cs[i] = 0.f;
    __syncthreads();

    // update-phase element ownership: i = tid + it*TPB over [0, 16*160)
    int er[EIT], ej[EIT];
#pragma unroll
    for (int it = 0; it < EIT; ++it) {
        int i = tid + it * TPB;
        er[it] = i / 160;
        ej[it] = i - er[it] * 160;
    }

    for (int s = 0; s < T_; ++s) {
        int t = cb.bwd ? (T_ - 1 - s) : s;

        // ---- prefetch xw (consumed after MFMA phase) ----
        float xi[EIT], xf_[EIT], xg[EIT], xo[EIT];
#pragma unroll
        for (int it = 0; it < EIT; ++it) {
            int r = er[it], j = ej[it];
            const float* xr;
            if (cb.gIn) {
                int g = args.inv[t * cb.Bn + row0 + r];
                xr = (g >= 0) ? cb.xw + (size_t)g * G_ : cb.bias;
            } else {
                xr = cb.xw + ((size_t)t * cb.Bn + row0 + r) * G_;
            }
            bool act = (j < H_);
            xi[it]  = act ? xr[j] : 0.f;
            xf_[it] = act ? xr[H_ + j] : 0.f;
            xg[it]  = act ? xr[2 * H_ + j] : 0.f;
            xo[it]  = act ? xr[3 * H_ + j] : 0.f;
        }

        // ---- A fragments (h) from pre-split LDS planes: 10 x ds_read_b128 ----
        bf16x8 ahi[KT_], alo[KT_];
#pragma unroll
        for (int kt = 0; kt < KT_; ++kt) {
            int off = col16 * HSTR + kt * 32 + quad * 8;
            ahi[kt] = *(const bf16x8*)&hsh[off];
            alo[kt] = *(const bf16x8*)&hsl[off];
        }

        // ---- MFMA: gates_h = h @ WhhT, emulated fp32 via 3x bf16; 2 acc chains ----
        for (int nt = wv; nt < NT_; nt += 8) {
            f32x4 a0 = {0.f, 0.f, 0.f, 0.f};
            f32x4 a1 = {0.f, 0.f, 0.f, 0.f};
            const bf16x8* bp = (const bf16x8*)cb.wpk + ((size_t)nt * KT_) * 2 * 64 + lane;
#pragma unroll
            for (int kt = 0; kt < KT_; ++kt) {
                bf16x8 bhi = bp[0];
                bf16x8 blo = bp[64];
                bp += 128;
                if (kt < 3) {
                    a0 = __builtin_amdgcn_mfma_f32_16x16x32_bf16(ahi[kt], bhi, a0, 0, 0, 0);
                    a0 = __builtin_amdgcn_mfma_f32_16x16x32_bf16(ahi[kt], blo, a0, 0, 0, 0);
                    a0 = __builtin_amdgcn_mfma_f32_16x16x32_bf16(alo[kt], bhi, a0, 0, 0, 0);
                } else {
                    a1 = __builtin_amdgcn_mfma_f32_16x16x32_bf16(ahi[kt], bhi, a1, 0, 0, 0);
                    a1 = __builtin_amdgcn_mfma_f32_16x16x32_bf16(ahi[kt], blo, a1, 0, 0, 0);
                    a1 = __builtin_amdgcn_mfma_f32_16x16x32_bf16(alo[kt], bhi, a1, 0, 0, 0);
                }
            }
            f32x4 acc = a0 + a1;
#pragma unroll
            for (int p = 0; p < 4; ++p)
                gs[(quad * 4 + p) * GST + nt * 16 + col16] = acc[p];
        }
        __syncthreads();

        // ---- gate combine + state update + output + h re-split write ----
#pragma unroll
        for (int it = 0; it < EIT; ++it) {
            int r = er[it], j = ej[it];
            if (j < H_) {
                float gi = gs[r * GST + j] + xi[it];
                float gf = gs[r * GST + H_ + j] + xf_[it];
                float gg = gs[r * GST + 2 * H_ + j] + xg[it];
                float go = gs[r * GST + 3 * H_ + j] + xo[it];
                float ii = fsig(gi), ff = fsig(gf), oo = fsig(go);
                float cc = ff * cs[r * 152 + j] + ii * ftanh(gg);
                float hh = oo * ftanh(cc);
                cs[r * 152 + j] = cc;
                unsigned u = __float_as_uint(hh);
                hsh[r * HSTR + j] = (unsigned short)(u >> 16);
                float hf = __uint_as_float(u & 0xffff0000u);
                hsl[r * HSTR + j] = (unsigned short)(__float_as_uint(hh - hf) >> 16);
                if (cb.gOut) {
                    int g = args.inv[t * cb.Bn + row0 + r];
                    if (g >= 0) {
                        size_t o = (size_t)g * O_ + cb.colOff + j;
                        if (args.addSrc)
                            cb.out[o] = (args.addSrc[o] + hh) * args.umask[g];
                        else
                            cb.out[o] = hh;
                    }
                } else {
                    cb.out[((size_t)t * cb.Bn + row0 + r) * O_ + cb.colOff + j] = hh;
                }
            }
        }
        __syncthreads();
    }
}

// ---------------- final add: out = (emotions + U_p) * umask ----------------
__global__ void k_add(const float* __restrict__ a, const float* __restrict__ b,
                      const float* __restrict__ um, float* __restrict__ out) {
    int idx = blockIdx.x * 256 + threadIdx.x;
    if (idx < T_ * B_ * O_)
        out[idx] = (a[idx] + b[idx]) * um[idx / O_];
}

extern "C" void kernel_launch(void* const* d_in, const int* in_sizes, int n_in,
                              void* d_out, int out_size, void* d_ws, size_t ws_size,
                              hipStream_t stream) {
    const float* U        = (const float*)d_in[0];
    const int*   qmask    = (const int*)d_in[1];
    const float* umask    = (const float*)d_in[2];
    const float* rnn_Wih0 = (const float*)d_in[4];
    const float* rnn_Whh0 = (const float*)d_in[5];
    const float* rnn_b0   = (const float*)d_in[6];
    const float* rnn_Wih1 = (const float*)d_in[7];
    const float* rnn_Whh1 = (const float*)d_in[8];
    const float* rnn_b1   = (const float*)d_in[9];
    const float* pr_Wih0  = (const float*)d_in[10];
    const float* pr_Whh0  = (const float*)d_in[11];
    const float* pr_b0    = (const float*)d_in[12];
    const float* pr_Wih1  = (const float*)d_in[13];
    const float* pr_Whh1  = (const float*)d_in[14];
    const float* pr_b1    = (const float*)d_in[15];

    int tier;
    if (ws_size >= total_words6() * 4ull) tier = 6;
    else if (ws_size >= total_words(4) * 4ull) tier = 4;
    else tier = 2;
    const int nslots = (tier >= 4) ? 4 : 2;

    float* ws    = (float*)d_ws;
    int*   inv   = (int*)d_ws + INV_OFF;
    float* wihT0 = ws + WIHT0_OFF;
    float* wihT1 = ws + WIHT1_OFF;
    unsigned short* wpk = (unsigned short*)(ws + WPK_OFF);

    const size_t W0S = 1024ull * 600, W1S = 300ull * 600;
    const size_t WPS = (size_t)NT_ * KT_ * 2 * 512;   // shorts per combo

    k_pos<<<dim3(1), dim3(256), 0, stream>>>(qmask, inv);

    auto TP = [&](const float* src, float* dst, int K) {
        int total = K * G_;
        k_transpose<<<dim3((total + 255) / 256), dim3(256), 0, stream>>>(src, dst, K);
    };
    for (int d = 0; d < 2; ++d) {
        TP(rnn_Wih0 + (size_t)d * G_ * D_, wihT0 + (0 + d) * W0S, D_);
        TP(pr_Wih0  + (size_t)d * G_ * D_, wihT0 + (2 + d) * W0S, D_);
        TP(rnn_Wih1 + (size_t)d * G_ * O_, wihT1 + (0 + d) * W1S, O_);
        TP(pr_Wih1  + (size_t)d * G_ * O_, wihT1 + (2 + d) * W1S, O_);
    }

    // pack all 8 Whh into MFMA B-fragment hi/lo layout
    PackArgs pa;
    for (int d = 0; d < 2; ++d) {
        pa.whh[0 + d] = rnn_Whh0 + (size_t)d * G_ * H_;
        pa.whh[2 + d] = pr_Whh0  + (size_t)d * G_ * H_;
        pa.whh[4 + d] = rnn_Whh1 + (size_t)d * G_ * H_;
        pa.whh[6 + d] = pr_Whh1  + (size_t)d * G_ * H_;
    }
    {
        int lanes = 8 * NT_ * KT_ * 64;
        k_pack<<<dim3((lanes + 255) / 256), dim3(256), 0, stream>>>(pa, wpk);
    }

    dim3 blk(256);
    dim3 sblk(TPB);
    dim3 g32k(10, 256);    // M = 32768
    dim3 g64k(10, 512);    // M = 65536
    const int INF = 0x7fffffff;

    ScanArgs z = {};
    auto setCombo = [&](ScanArgs& sa, int i, const float* xw, int wslot,
                        const float* bi, float* o, int Bn, int co, int bw,
                        int gi, int go) {
        sa.c[i].xw = xw; sa.c[i].wpk = wpk + (size_t)wslot * WPS;
        sa.c[i].bias = bi; sa.c[i].out = o;
        sa.c[i].Bn = Bn; sa.c[i].colOff = co; sa.c[i].bwd = bw;
        sa.c[i].gIn = gi; sa.c[i].gOut = go;
    };

    if (tier == 6) {
        float* X[6];
        for (int i = 0; i < 6; ++i) X[i] = ws + XW_OFF + (size_t)i * XSLOT;
        float* h_rnn = ws + hrnn_off6();
        float* h_pr  = ws + hpr_off6();
        float* U_p   = h_pr;   // h_pr region is free during the merged scan

        // ---- layer 0: four GEMMs, one 96-block scan ----
        k_gemm<<<g32k, blk, 0, stream>>>(U, wihT0 + 0 * W0S, rnn_b0 + 0 * G_, X[0], 32768, D_);
        k_gemm<<<g32k, blk, 0, stream>>>(U, wihT0 + 1 * W0S, rnn_b0 + 1 * G_, X[1], 32768, D_);
        k_gemm<<<g32k, blk, 0, stream>>>(U, wihT0 + 2 * W0S, pr_b0 + 0 * G_, X[2], 32768, D_);
        k_gemm<<<g32k, blk, 0, stream>>>(U, wihT0 + 3 * W0S, pr_b0 + 1 * G_, X[3], 32768, D_);
        ScanArgs sa = z;
        sa.inv = inv;
        setCombo(sa, 0, X[0], 0, nullptr, h_rnn, B_, 0, 0, 0, 0);
        setCombo(sa, 1, X[1], 1, nullptr, h_rnn, B_, H_, 1, 0, 0);
        setCombo(sa, 2, X[2], 2, pr_b0 + 0 * G_, h_pr, BP, 0, 0, 1, 0);
        setCombo(sa, 3, X[3], 3, pr_b0 + 1 * G_, h_pr, BP, H_, 1, 1, 0);
        sa.blkStart[0] = 0; sa.blkStart[1] = 16; sa.blkStart[2] = 32;
        sa.blkStart[3] = 64; sa.blkStart[4] = 96;
        k_scan<<<dim3(96), sblk, 0, stream>>>(sa);

        // ---- layer 1: all four GEMMs, then one merged 96-block scan ----
        k_gemm<<<g32k, blk, 0, stream>>>(h_rnn, wihT1 + 0 * W1S, rnn_b1 + 0 * G_, X[0], 32768, O_);
        k_gemm<<<g32k, blk, 0, stream>>>(h_rnn, wihT1 + 1 * W1S, rnn_b1 + 1 * G_, X[1], 32768, O_);
        k_gemm<<<g64k, blk, 0, stream>>>(h_pr, wihT1 + 2 * W1S, pr_b1 + 0 * G_, X[2], 65536, O_);  // spans X2,X3
        k_gemm<<<g64k, blk, 0, stream>>>(h_pr, wihT1 + 3 * W1S, pr_b1 + 1 * G_, X[4], 65536, O_);  // spans X4,X5
        ScanArgs sm = z;
        sm.inv = inv; sm.addSrc = nullptr; sm.umask = nullptr;
        setCombo(sm, 0, X[0], 4, nullptr, h_rnn, B_, 0, 0, 0, 0);
        setCombo(sm, 1, X[1], 5, nullptr, h_rnn, B_, H_, 1, 0, 0);
        setCombo(sm, 2, X[2], 6, nullptr, U_p, BP, 0, 0, 0, 1);
        setCombo(sm, 3, X[4], 7, nullptr, U_p, BP, H_, 1, 0, 1);
        sm.blkStart[0] = 0; sm.blkStart[1] = 16; sm.blkStart[2] = 32;
        sm.blkStart[3] = 64; sm.blkStart[4] = 96;
        k_scan<<<dim3(96), sblk, 0, stream>>>(sm);

        // ---- out = (emotions + U_p) * umask ----
        k_add<<<dim3((T_ * B_ * O_ + 255) / 256), dim3(256), 0, stream>>>(
            h_rnn, U_p, umask, (float*)d_out);
        return;
    }

    float* X0    = ws + XW_OFF;
    float* X1    = X0 + XSLOT;
    float* X2    = (nslots == 4) ? X1 + XSLOT : X0;
    float* X3    = (nslots == 4) ? X2 + XSLOT : X1;
    float* h_rnn = ws + hrnn_off(nslots);
    float* h_pr  = ws + hpr_off(nslots);

    if (nslots == 4) {
        // ---- layer 0: four GEMMs, one 96-block scan ----
        k_gemm<<<g32k, blk, 0, stream>>>(U, wihT0 + 0 * W0S, rnn_b0 + 0 * G_, X0, 32768, D_);
        k_gemm<<<g32k, blk, 0, stream>>>(U, wihT0 + 1 * W0S, rnn_b0 + 1 * G_, X1, 32768, D_);
        k_gemm<<<g32k, blk, 0, stream>>>(U, wihT0 + 2 * W0S, pr_b0 + 0 * G_, X2, 32768, D_);
        k_gemm<<<g32k, blk, 0, stream>>>(U, wihT0 + 3 * W0S, pr_b0 + 1 * G_, X3, 32768, D_);
        ScanArgs sa = z;
        sa.inv = inv;
        setCombo(sa, 0, X0, 0, nullptr, h_rnn, B_, 0, 0, 0, 0);
        setCombo(sa, 1, X1, 1, nullptr, h_rnn, B_, H_, 1, 0, 0);
        setCombo(sa, 2, X2, 2, pr_b0 + 0 * G_, h_pr, BP, 0, 0, 1, 0);
        setCombo(sa, 3, X3, 3, pr_b0 + 1 * G_, h_pr, BP, H_, 1, 1, 0);
        sa.blkStart[0] = 0; sa.blkStart[1] = 16; sa.blkStart[2] = 32;
        sa.blkStart[3] = 64; sa.blkStart[4] = 96;
        k_scan<<<dim3(96), sblk, 0, stream>>>(sa);

        // ---- layer 1 rnn GEMMs + pr-d0 GEMM, rnn scan ----
        k_gemm<<<g32k, blk, 0, stream>>>(h_rnn, wihT1 + 0 * W1S, rnn_b1 + 0 * G_, X0, 32768, O_);
        k_gemm<<<g32k, blk, 0, stream>>>(h_rnn, wihT1 + 1 * W1S, rnn_b1 + 1 * G_, X1, 32768, O_);
        k_gemm<<<g64k, blk, 0, stream>>>(h_pr, wihT1 + 2 * W1S, pr_b1 + 0 * G_, X2, 65536, O_);
        ScanArgs sr = z;
        sr.inv = inv;
        setCombo(sr, 0, X0, 4, nullptr, h_rnn, B_, 0, 0, 0, 0);
        setCombo(sr, 1, X1, 5, nullptr, h_rnn, B_, H_, 1, 0, 0);
        sr.blkStart[0] = 0; sr.blkStart[1] = 16; sr.blkStart[2] = INF;
        sr.blkStart[3] = INF; sr.blkStart[4] = 32;
        k_scan<<<dim3(32), sblk, 0, stream>>>(sr);

        // ---- layer 1 pr-d1 GEMM (into freed X0+X1), fused final scan ----
        k_gemm<<<g64k, blk, 0, stream>>>(h_pr, wihT1 + 3 * W1S, pr_b1 + 1 * G_, X0, 65536, O_);
        ScanArgs sp = z;
        sp.inv = inv; sp.addSrc = h_rnn; sp.umask = umask;
        setCombo(sp, 0, X2, 6, nullptr, (float*)d_out, BP, 0, 0, 0, 1);
        setCombo(sp, 1, X0, 7, nullptr, (float*)d_out, BP, H_, 1, 0, 1);
        sp.blkStart[0] = 0; sp.blkStart[1] = 32; sp.blkStart[2] = INF;
        sp.blkStart[3] = INF; sp.blkStart[4] = 64;
        k_scan<<<dim3(64), sblk, 0, stream>>>(sp);
    } else {
        // ---- small-workspace phased path ----
        for (int d = 0; d < 2; ++d) {
            k_gemm<<<g32k, blk, 0, stream>>>(U, wihT0 + (0 + d) * W0S, rnn_b0 + d * G_, X0, 32768, D_);
            k_gemm<<<g32k, blk, 0, stream>>>(U, wihT0 + (2 + d) * W0S, pr_b0 + d * G_, X1, 32768, D_);
            ScanArgs sa = z;
            sa.inv = inv;
            setCombo(sa, 0, X0, 0 + d, nullptr, h_rnn, B_, d * H_, d, 0, 0);
            setCombo(sa, 1, X1, 2 + d, pr_b0 + d * G_, h_pr, BP, d * H_, d, 1, 0);
            sa.blkStart[0] = 0; sa.blkStart[1] = 16; sa.blkStart[2] = INF;
            sa.blkStart[3] = INF; sa.blkStart[4] = 48;
            k_scan<<<dim3(48), sblk, 0, stream>>>(sa);
        }
        k_gemm<<<g32k, blk, 0, stream>>>(h_rnn, wihT1 + 0 * W1S, rnn_b1 + 0 * G_, X0, 32768, O_);
        k_gemm<<<g32k, blk, 0, stream>>>(h_rnn, wihT1 + 1 * W1S, rnn_b1 + 1 * G_, X1, 32768, O_);
        {
            ScanArgs sr = z;
            sr.inv = inv;
            setCombo(sr, 0, X0, 4, nullptr, h_rnn, B_, 0, 0, 0, 0);
            setCombo(sr, 1, X1, 5, nullptr, h_rnn, B_, H_, 1, 0, 0);
            sr.blkStart[0] = 0; sr.blkStart[1] = 16; sr.blkStart[2] = INF;
            sr.blkStart[3] = INF; sr.blkStart[4] = 32;
            k_scan<<<dim3(32), sblk, 0, stream>>>(sr);
        }
        for (int d = 0; d < 2; ++d) {
            k_gemm<<<g64k, blk, 0, stream>>>(h_pr, wihT1 + (2 + d) * W1S, pr_b1 + d * G_, X0, 65536, O_);
            ScanArgs sp = z;
            sp.inv = inv; sp.addSrc = h_rnn; sp.umask = umask;
            setCombo(sp, 0, X0, 6 + d, nullptr, (float*)d_out, BP, d * H_, d, 0, 1);
            sp.blkStart[0] = 0; sp.blkStart[1] = INF; sp.blkStart[2] = INF;
            sp.blkStart[3] = INF; sp.blkStart[4] = 32;
            k_scan<<<dim3(32), sblk, 0, stream>>>(sp);
        }
    }
}

// Round 2
// 4103.146 us; speedup vs baseline: 1.9499x; 1.5082x over previous
//
#include <hip/hip_runtime.h>
#include <hip/hip_bf16.h>
#include <math.h>

#define T_ 128
#define B_ 256
#define BP 512     // 2B (party batch)
#define D_ 1024
#define H_ 150
#define G_ 600     // 4H
#define O_ 300     // 2H
#define ROWS 16    // batch rows per scan block (one MFMA M-tile)
#define NT_ 38     // n-tiles of 16 covering 600 (608)
#define KT_ 5      // k-tiles of 32 covering 150 (160)
#define HSTR 168   // h hi/lo plane row stride in ushorts (16B-aligned, 2-way-free b128 frag reads)
#define GST 620    // gs row stride in floats (620%32=12 -> <=2-way on acc scatter)
#define TPB 512    // scan threads per block (8 waves)
#define EIT 5      // update-phase elems/thread: 16*160/512
#define NTB 38     // GEMM B n-tiles packed (608 cols; blocks guard nt>=38)

typedef float v4f    __attribute__((ext_vector_type(4)));
typedef short bf16x8 __attribute__((ext_vector_type(8)));
typedef float f32x4  __attribute__((ext_vector_type(4)));
typedef unsigned int u32x4 __attribute__((ext_vector_type(4)));
union HU { u32x4 u; bf16x8 h; };

// ---------------- NEW workspace layout (4-byte words) ----------------
// inv | wpk(scan Whh frags) | bpk(GEMM B frags, L0 4 combos; L1 reuses) |
// hreg { h_rnn 9.83M, h_pr 19.66M ; Upk(half-M planes 16.78M) aliased at start } |
// X x4 slots
static const size_t N_INV   = 0;                         // int[128*512] = 65,536 words
static const size_t N_WPK   = 65536;                     // 778,240 words
static const size_t N_BPK   = N_WPK + 778240;            // 2,490,368 words (4 x 622,592)
static const size_t N_HREG  = N_BPK + 2490368;           // 29,491,200 words
static const size_t N_X     = N_HREG + 29491200;         // 4 x 19,660,800
static const size_t N_TOTAL = N_X + 78643200 + 256;      // ~445.9 MB

static const size_t BPK0_STR = 1245184;  // shorts per layer-0 combo (32*38*2*512)
static const size_t BPK1_STR = 389120;   // shorts per layer-1 combo (10*38*2*512)

// ---------------- legacy layout (fallback only) ----------------
static const size_t INV_OFF   = 0;
static const size_t WIHT0_OFF = 65536;
static const size_t WIHT1_OFF = WIHT0_OFF + 4ull * 1024 * 600;
static const size_t WPK_OFF   = WIHT1_OFF + 4ull * 300 * 600;
static const size_t WPK_WORDS = 8ull * NT_ * KT_ * 2 * 512 / 2;
static const size_t XW_OFF    = WPK_OFF + WPK_WORDS;
static const size_t XSLOT     = 32768ull * 600;
static size_t hrnn_off(int nslots) { return XW_OFF + (size_t)nslots * XSLOT; }
static size_t hpr_off(int nslots)  { return hrnn_off(nslots) + 32768ull * 300; }
static size_t total_words(int nslots) { return hpr_off(nslots) + 65536ull * 300; }

// ---------------- fast transcendentals ----------------
__device__ __forceinline__ float fsig(float x) {
    return __builtin_amdgcn_rcpf(1.f + __expf(-x));
}
__device__ __forceinline__ float ftanh(float x) {
    float xc = fminf(fmaxf(x, -15.f), 15.f);
    float e = __expf(-2.f * xc);
    return (1.f - e) * __builtin_amdgcn_rcpf(1.f + e);
}

// ---------------- inverse map: (pos p, party row) -> dialogue row or -1 ----------
__global__ void k_pos(const int* __restrict__ qmask, int* __restrict__ inv) {
    int b = threadIdx.x;
    for (int p = 0; p < T_; ++p) {
        inv[p * BP + b] = -1;
        inv[p * BP + B_ + b] = -1;
    }
    int c0 = 0, c1 = 0;
    for (int t = 0; t < T_; ++t) {
        int s = qmask[(t * B_ + b) * 2 + 1];
        int p = s ? c1++ : c0++;
        inv[p * BP + s * B_ + b] = t * B_ + b;
    }
}

// ---------------- transpose W[g][k] -> WT[k][g] (legacy fallback) ----------------
__global__ void k_transpose(const float* __restrict__ src, float* __restrict__ dst,
                            int K) {
    int idx = blockIdx.x * 256 + threadIdx.x;
    int total = K * G_;
    if (idx < total) {
        int k = idx / G_, g = idx - k * G_;
        dst[idx] = src[(size_t)g * K + k];
    }
}

// ---------------- pack Whh[600][150] into MFMA B-fragment layout (scan) ----------
struct PackArgs { const float* whh[8]; };
__global__ void k_pack(PackArgs pa, unsigned short* __restrict__ wpk) {
    int gid = blockIdx.x * 256 + threadIdx.x;
    int lane = gid & 63;
    int q = gid >> 6;
    int kt = q % KT_; q /= KT_;
    int nt = q % NT_; q /= NT_;
    if (q >= 8) return;
    const float* W = pa.whh[q];
    int col = nt * 16 + (lane & 15);
    int kbase = kt * 32 + (lane >> 4) * 8;
    size_t base = ((((size_t)q * NT_ + nt) * KT_ + kt) * 2) * 512 + (size_t)lane * 8;
    for (int j = 0; j < 8; ++j) {
        int k = kbase + j;
        float v = (col < G_ && k < H_) ? W[(size_t)col * H_ + k] : 0.f;
        unsigned u = __float_as_uint(v);
        unsigned short hi = (unsigned short)(u >> 16);
        float hf = __uint_as_float(u & 0xffff0000u);
        unsigned short lo = (unsigned short)(__float_as_uint(v - hf) >> 16);
        wpk[base + j] = hi;
        wpk[base + 512 + j] = lo;
    }
}

// ---------------- pack Wih[600][K] into GEMM B-fragment hi/lo layout --------------
// out layout: [kt][nt(38)][hi/lo][lane][8]; zeros for k>=K or col>=600
__global__ void k_packB(const float* __restrict__ W, int K, int KT,
                        unsigned short* __restrict__ out) {
    int gid = blockIdx.x * 256 + threadIdx.x;
    int lane = gid & 63, q = gid >> 6;
    int kt = q % KT, nt = q / KT;
    if (nt >= NTB) return;
    int col = nt * 16 + (lane & 15);
    int kb = kt * 32 + (lane >> 4) * 8;
    size_t base = ((size_t)(kt * NTB + nt) * 2) * 512 + (size_t)lane * 8;
    bf16x8 h8 = {0, 0, 0, 0, 0, 0, 0, 0};
    bf16x8 l8 = {0, 0, 0, 0, 0, 0, 0, 0};
#pragma unroll
    for (int j = 0; j < 8; ++j) {
        int k = kb + j;
        float v = (col < G_ && k < K) ? W[(size_t)col * K + k] : 0.f;
        unsigned u = __float_as_uint(v);
        h8[j] = (short)(u >> 16);
        float hf = __uint_as_float(u & 0xffff0000u);
        l8[j] = (short)(__float_as_uint(v - hf) >> 16);
    }
    *(bf16x8*)(out + base) = h8;
    *(bf16x8*)(out + base + 512) = l8;
}

// ---------------- pack U half (16384 rows x 1024) into A-fragment planes ----------
// plane layout (shorts): off(m,k) = (((m>>4)*128 + (k>>3))*16 + (m&15))*8 + (k&7)
__global__ void k_packU(const float* __restrict__ A, unsigned short* __restrict__ hi,
                        unsigned short* __restrict__ lo) {
    int gid = blockIdx.x * 256 + threadIdx.x;     // < 16384*128
    int kc = gid & 127, rr = gid >> 7;
    const float* ap = A + (size_t)rr * 1024 + kc * 8;
    size_t off = ((size_t)((rr >> 4) * 128 + kc) * 16 + (rr & 15)) * 8;
    bf16x8 h8, l8;
#pragma unroll
    for (int j = 0; j < 8; ++j) {
        float v = ap[j];
        unsigned u = __float_as_uint(v);
        h8[j] = (short)(u >> 16);
        float hf = __uint_as_float(u & 0xffff0000u);
        l8[j] = (short)(__float_as_uint(v - hf) >> 16);
    }
    *(bf16x8*)(hi + off) = h8;
    *(bf16x8*)(lo + off) = l8;
}

// ---------------- in-place recode fp32 -> (hi16<<16)|lo16 ------------------------
__global__ void k_recode(unsigned int* __restrict__ p, int n4) {
    int gid = blockIdx.x * 256 + threadIdx.x;
    if (gid >= n4) return;
    u32x4 w = *(u32x4*)(p + (size_t)gid * 4);
#pragma unroll
    for (int j = 0; j < 4; ++j) {
        unsigned u = w[j];
        float v = __uint_as_float(u);
        float hf = __uint_as_float(u & 0xffff0000u);
        w[j] = (u & 0xffff0000u) | (__float_as_uint(v - hf) >> 16);
    }
    *(u32x4*)(p + (size_t)gid * 4) = w;
}

// ---------------- MFMA GEMM: C[M,600] = A[M,K] @ W^T + bias, split-bf16 ----------
// MODE 0: A from packed hi/lo planes (layer 0, K=1024, KA=K/8=128)
// MODE 1: A from in-place-recoded u32 rows (layer 1, K=300=KA; B zero-padded k>=300)
// 128x128 tile, 4 waves (2x2), 64x64 per wave, no LDS, 2-slot pipeline.

#define LOADK(kt_, S)                                                          \
  {                                                                            \
    if (MODE == 0) {                                                           \
      _Pragma("unroll") for (int mi = 0; mi < 4; ++mi) {                       \
        size_t aoff = ((size_t)((m0 >> 4) + mi) * KA + (kt_) * 4 + quad);      \
        aoff = (aoff * 16 + col16) * 8;                                        \
        a_h##S[mi] = *(const bf16x8*)(Ahi + aoff);                             \
        a_l##S[mi] = *(const bf16x8*)(Alo + aoff);                             \
      }                                                                        \
    } else {                                                                   \
      _Pragma("unroll") for (int mi = 0; mi < 4; ++mi) {                       \
        const unsigned int* ap =                                               \
            Aw + (size_t)(m0 + mi * 16 + col16) * KA + (kt_) * 32 + quad * 8;  \
        u32x4 w0 = *(const u32x4*)ap;                                          \
        u32x4 w1 = *(const u32x4*)(ap + 4);                                    \
        HU hh, ll;                                                             \
        hh.u.x = (w0.x >> 16) | (w0.y & 0xffff0000u);                          \
        hh.u.y = (w0.z >> 16) | (w0.w & 0xffff0000u);                          \
        hh.u.z = (w1.x >> 16) | (w1.y & 0xffff0000u);                          \
        hh.u.w = (w1.z >> 16) | (w1.w & 0xffff0000u);                          \
        ll.u.x = (w0.x & 0xffffu) | (w0.y << 16);                              \
        ll.u.y = (w0.z & 0xffffu) | (w0.w << 16);                              \
        ll.u.z = (w1.x & 0xffffu) | (w1.y << 16);                              \
        ll.u.w = (w1.z & 0xffffu) | (w1.w << 16);                              \
        a_h##S[mi] = hh.h;                                                     \
        a_l##S[mi] = ll.h;                                                     \
      }                                                                        \
    }                                                                          \
    _Pragma("unroll") for (int ni = 0; ni < 4; ++ni) {                         \
      if (bnv[ni]) {                                                           \
        size_t bo = ((size_t)((kt_) * NTB + nt0 + ni) * 2) * 512 + lane * 8;   \
        b_h##S[ni] = *(const bf16x8*)(Bpk + bo);                               \
        b_l##S[ni] = *(const bf16x8*)(Bpk + bo + 512);                         \
      }                                                                        \
    }                                                                          \
  }

#define MMK(S)                                                                 \
  _Pragma("unroll") for (int mi = 0; mi < 4; ++mi)                             \
    _Pragma("unroll") for (int ni = 0; ni < 4; ++ni) {                         \
      acc[mi][ni] = __builtin_amdgcn_mfma_f32_16x16x32_bf16(                   \
          a_h##S[mi], b_h##S[ni], acc[mi][ni], 0, 0, 0);                       \
      acc[mi][ni] = __builtin_amdgcn_mfma_f32_16x16x32_bf16(                   \
          a_h##S[mi], b_l##S[ni], acc[mi][ni], 0, 0, 0);                       \
      acc[mi][ni] = __builtin_amdgcn_mfma_f32_16x16x32_bf16(                   \
          a_l##S[mi], b_h##S[ni], acc[mi][ni], 0, 0, 0);                       \
    }

template<int MODE, int KTN, int KA>
__global__ __launch_bounds__(256) void k_mgemm(const unsigned short* __restrict__ Ahi,
                                               const unsigned short* __restrict__ Alo,
                                               const unsigned int* __restrict__ Aw,
                                               const unsigned short* __restrict__ Bpk,
                                               const float* __restrict__ bias,
                                               float* __restrict__ C) {
    int tid = threadIdx.x, lane = tid & 63, wv = tid >> 6;
    int col16 = lane & 15, quad = lane >> 4;
    int n0 = blockIdx.x * 128 + (wv & 1) * 64;
    int m0 = blockIdx.y * 128 + (wv >> 1) * 64;
    int nt0 = n0 >> 4;

    bool bnv[4]; float bs[4];
#pragma unroll
    for (int ni = 0; ni < 4; ++ni) {
        int nt = nt0 + ni;
        bnv[ni] = (nt < NTB);
        int cc = nt * 16 + col16;
        bs[ni] = (cc < G_) ? bias[cc] : 0.f;
    }

    f32x4 acc[4][4];
#pragma unroll
    for (int mi = 0; mi < 4; ++mi)
#pragma unroll
        for (int ni = 0; ni < 4; ++ni) acc[mi][ni] = (f32x4){0.f, 0.f, 0.f, 0.f};

    bf16x8 z8 = {0, 0, 0, 0, 0, 0, 0, 0};
    bf16x8 a_h0[4], a_l0[4], b_h0[4], b_l0[4];
    bf16x8 a_h1[4], a_l1[4], b_h1[4], b_l1[4];
#pragma unroll
    for (int ni = 0; ni < 4; ++ni) {
        b_h0[ni] = z8; b_l0[ni] = z8; b_h1[ni] = z8; b_l1[ni] = z8;
    }

    LOADK(0, 0);
#pragma unroll 1
    for (int kt = 0; kt < KTN; kt += 2) {
        LOADK(kt + 1, 1);
        MMK(0);
        if (kt + 2 < KTN) { LOADK(kt + 2, 0); }
        MMK(1);
    }

#pragma unroll
    for (int mi = 0; mi < 4; ++mi)
#pragma unroll
        for (int ni = 0; ni < 4; ++ni) {
            int col = n0 + ni * 16 + col16;
            if (col < G_) {
#pragma unroll
                for (int p = 0; p < 4; ++p)
                    C[(size_t)(m0 + mi * 16 + quad * 4 + p) * G_ + col] =
                        acc[mi][ni][p] + bs[ni];
            }
        }
}

// ---------------- legacy fp32 GEMM (fallback path only) ----------------
__global__ __launch_bounds__(256) void k_gemm(const float* __restrict__ A,
                                              const float* __restrict__ BT,
                                              const float* __restrict__ bias,
                                              float* __restrict__ C,
                                              int M, int K) {
    __shared__ __align__(16) float As[16][136];
    __shared__ __align__(16) float Bs[16][68];
    int n0 = blockIdx.x * 64, m0 = blockIdx.y * 128;
    int tid = threadIdx.x;
    int tx = tid & 15, ty = tid >> 4;
    int ar = tid >> 2, ac = (tid & 3) * 4;
    int kr = tid >> 4, nc = (tid & 15) * 4;
    float acc[8][4];
#pragma unroll
    for (int i = 0; i < 8; ++i)
#pragma unroll
        for (int j = 0; j < 4; ++j) acc[i][j] = 0.f;

    for (int k0 = 0; k0 < K; k0 += 16) {
        bool fullK = (k0 + 16 <= K);
#pragma unroll
        for (int half = 0; half < 2; ++half) {
            int m = m0 + ar + half * 64;
            const float* ap = A + (size_t)m * K + k0 + ac;
            if (fullK) {
                v4f v = *(const v4f*)ap;
                As[ac + 0][ar + half * 64] = v.x;
                As[ac + 1][ar + half * 64] = v.y;
                As[ac + 2][ar + half * 64] = v.z;
                As[ac + 3][ar + half * 64] = v.w;
            } else {
#pragma unroll
                for (int i = 0; i < 4; ++i) {
                    int k = k0 + ac + i;
                    As[ac + i][ar + half * 64] = (k < K) ? ap[i] : 0.f;
                }
            }
        }
        {
            int k = k0 + kr, n = n0 + nc;
            if (fullK && n + 3 < G_) {
                v4f v = *(const v4f*)(BT + (size_t)k * G_ + n);
                Bs[kr][nc + 0] = v.x; Bs[kr][nc + 1] = v.y;
                Bs[kr][nc + 2] = v.z; Bs[kr][nc + 3] = v.w;
            } else {
#pragma unroll
                for (int i = 0; i < 4; ++i) {
                    int nn = n + i;
                    Bs[kr][nc + i] = (k < K && nn < G_) ? BT[(size_t)k * G_ + nn] : 0.f;
                }
            }
        }
        __syncthreads();
#pragma unroll
        for (int kk = 0; kk < 16; ++kk) {
            v4f a0 = *(const v4f*)&As[kk][ty * 8];
            v4f a1 = *(const v4f*)&As[kk][ty * 8 + 4];
            v4f b  = *(const v4f*)&Bs[kk][tx * 4];
            const float* af = (const float*)&a0;
            const float* af2 = (const float*)&a1;
            const float* bf = (const float*)&b;
#pragma unroll
            for (int i = 0; i < 4; ++i)
#pragma unroll
                for (int j = 0; j < 4; ++j) {
                    acc[i][j] += af[i] * bf[j];
                    acc[4 + i][j] += af2[i] * bf[j];
                }
        }
        __syncthreads();
    }
    int n = n0 + tx * 4;
    if (n + 3 < G_) {
        v4f bv = *(const v4f*)(bias + n);
#pragma unroll
        for (int i = 0; i < 8; ++i) {
            int m = m0 + ty * 8 + i;
            v4f o = {acc[i][0] + bv.x, acc[i][1] + bv.y, acc[i][2] + bv.z, acc[i][3] + bv.w};
            *(v4f*)(C + (size_t)m * G_ + n) = o;
        }
    } else {
#pragma unroll
        for (int i = 0; i < 8; ++i) {
            int m = m0 + ty * 8 + i;
#pragma unroll
            for (int j = 0; j < 4; ++j)
                if (n + j < G_) C[(size_t)m * G_ + n + j] = acc[i][j] + bias[n + j];
        }
    }
}

// ---------------- MFMA LSTM scan: 16 rows/block, 8 waves, split-bf16 fp32 --------
struct Combo {
    const float* xw;
    const unsigned short* wpk;
    const float* bias;
    float* out;
    int Bn, colOff, bwd, gIn, gOut;
};
struct ScanArgs {
    Combo c[4];
    const int* inv;
    const float* addSrc;
    const float* umask;
    int blkStart[5];
};

__global__ __launch_bounds__(TPB) void k_scan(ScanArgs args) {
    int bx = blockIdx.x, ci = 0;
#pragma unroll
    for (int i = 1; i < 4; ++i)
        if (bx >= args.blkStart[i]) ci = i;
    Combo cb = args.c[ci];
    int row0 = (bx - args.blkStart[ci]) * ROWS;

    __shared__ __align__(16) unsigned short hsh[ROWS * HSTR];
    __shared__ __align__(16) unsigned short hsl[ROWS * HSTR];
    __shared__ float cs[ROWS * 152];
    __shared__ float gs[ROWS * GST];
    int tid = threadIdx.x;
    int lane = tid & 63, wv = tid >> 6;
    int col16 = lane & 15, quad = lane >> 4;
    for (int i = tid; i < ROWS * HSTR; i += TPB) { hsh[i] = 0; hsl[i] = 0; }
    for (int i = tid; i < ROWS * 152; i += TPB) cs[i] = 0.f;
    __syncthreads();

    int er[EIT], ej[EIT];
#pragma unroll
    for (int it = 0; it < EIT; ++it) {
        int i = tid + it * TPB;
        er[it] = i / 160;
        ej[it] = i - er[it] * 160;
    }

    for (int s = 0; s < T_; ++s) {
        int t = cb.bwd ? (T_ - 1 - s) : s;

        float xi[EIT], xf_[EIT], xg[EIT], xo[EIT];
#pragma unroll
        for (int it = 0; it < EIT; ++it) {
            int r = er[it], j = ej[it];
            const float* xr;
            if (cb.gIn) {
                int g = args.inv[t * cb.Bn + row0 + r];
                xr = (g >= 0) ? cb.xw + (size_t)g * G_ : cb.bias;
            } else {
                xr = cb.xw + ((size_t)t * cb.Bn + row0 + r) * G_;
            }
            bool act = (j < H_);
            xi[it]  = act ? xr[j] : 0.f;
            xf_[it] = act ? xr[H_ + j] : 0.f;
            xg[it]  = act ? xr[2 * H_ + j] : 0.f;
            xo[it]  = act ? xr[3 * H_ + j] : 0.f;
        }

        bf16x8 ahi[KT_], alo[KT_];
#pragma unroll
        for (int kt = 0; kt < KT_; ++kt) {
            int off = col16 * HSTR + kt * 32 + quad * 8;
            ahi[kt] = *(const bf16x8*)&hsh[off];
            alo[kt] = *(const bf16x8*)&hsl[off];
        }

        for (int nt = wv; nt < NT_; nt += 8) {
            f32x4 a0 = {0.f, 0.f, 0.f, 0.f};
            f32x4 a1 = {0.f, 0.f, 0.f, 0.f};
            const bf16x8* bp = (const bf16x8*)cb.wpk + ((size_t)nt * KT_) * 2 * 64 + lane;
#pragma unroll
            for (int kt = 0; kt < KT_; ++kt) {
                bf16x8 bhi = bp[0];
                bf16x8 blo = bp[64];
                bp += 128;
                if (kt < 3) {
                    a0 = __builtin_amdgcn_mfma_f32_16x16x32_bf16(ahi[kt], bhi, a0, 0, 0, 0);
                    a0 = __builtin_amdgcn_mfma_f32_16x16x32_bf16(ahi[kt], blo, a0, 0, 0, 0);
                    a0 = __builtin_amdgcn_mfma_f32_16x16x32_bf16(alo[kt], bhi, a0, 0, 0, 0);
                } else {
                    a1 = __builtin_amdgcn_mfma_f32_16x16x32_bf16(ahi[kt], bhi, a1, 0, 0, 0);
                    a1 = __builtin_amdgcn_mfma_f32_16x16x32_bf16(ahi[kt], blo, a1, 0, 0, 0);
                    a1 = __builtin_amdgcn_mfma_f32_16x16x32_bf16(alo[kt], bhi, a1, 0, 0, 0);
                }
            }
            f32x4 acc = a0 + a1;
#pragma unroll
            for (int p = 0; p < 4; ++p)
                gs[(quad * 4 + p) * GST + nt * 16 + col16] = acc[p];
        }
        __syncthreads();

#pragma unroll
        for (int it = 0; it < EIT; ++it) {
            int r = er[it], j = ej[it];
            if (j < H_) {
                float gi = gs[r * GST + j] + xi[it];
                float gf = gs[r * GST + H_ + j] + xf_[it];
                float gg = gs[r * GST + 2 * H_ + j] + xg[it];
                float go = gs[r * GST + 3 * H_ + j] + xo[it];
                float ii = fsig(gi), ff = fsig(gf), oo = fsig(go);
                float cc = ff * cs[r * 152 + j] + ii * ftanh(gg);
                float hh = oo * ftanh(cc);
                cs[r * 152 + j] = cc;
                unsigned u = __float_as_uint(hh);
                hsh[r * HSTR + j] = (unsigned short)(u >> 16);
                float hf = __uint_as_float(u & 0xffff0000u);
                hsl[r * HSTR + j] = (unsigned short)(__float_as_uint(hh - hf) >> 16);
                if (cb.gOut) {
                    int g = args.inv[t * cb.Bn + row0 + r];
                    if (g >= 0) {
                        size_t o = (size_t)g * O_ + cb.colOff + j;
                        if (args.addSrc)
                            cb.out[o] = (args.addSrc[o] + hh) * args.umask[g];
                        else
                            cb.out[o] = hh;
                    }
                } else {
                    cb.out[((size_t)t * cb.Bn + row0 + r) * O_ + cb.colOff + j] = hh;
                }
            }
        }
        __syncthreads();
    }
}

extern "C" void kernel_launch(void* const* d_in, const int* in_sizes, int n_in,
                              void* d_out, int out_size, void* d_ws, size_t ws_size,
                              hipStream_t stream) {
    const float* U        = (const float*)d_in[0];
    const int*   qmask    = (const int*)d_in[1];
    const float* umask    = (const float*)d_in[2];
    const float* rnn_Wih0 = (const float*)d_in[4];
    const float* rnn_Whh0 = (const float*)d_in[5];
    const float* rnn_b0   = (const float*)d_in[6];
    const float* rnn_Wih1 = (const float*)d_in[7];
    const float* rnn_Whh1 = (const float*)d_in[8];
    const float* rnn_b1   = (const float*)d_in[9];
    const float* pr_Wih0  = (const float*)d_in[10];
    const float* pr_Whh0  = (const float*)d_in[11];
    const float* pr_b0    = (const float*)d_in[12];
    const float* pr_Wih1  = (const float*)d_in[13];
    const float* pr_Whh1  = (const float*)d_in[14];
    const float* pr_b1    = (const float*)d_in[15];

    float* ws = (float*)d_ws;
    dim3 blk(256);
    dim3 sblk(TPB);
    const int INF = 0x7fffffff;

    const size_t WPS = (size_t)NT_ * KT_ * 2 * 512;   // shorts per scan-Whh combo

    ScanArgs z = {};
    auto setCombo = [&](ScanArgs& sa, int i, const float* xw, unsigned short* wbase,
                        int wslot, const float* bi, float* o, int Bn, int co, int bw,
                        int gi, int go) {
        sa.c[i].xw = xw; sa.c[i].wpk = wbase + (size_t)wslot * WPS;
        sa.c[i].bias = bi; sa.c[i].out = o;
        sa.c[i].Bn = Bn; sa.c[i].colOff = co; sa.c[i].bwd = bw;
        sa.c[i].gIn = gi; sa.c[i].gOut = go;
    };

    PackArgs pa;
    for (int d = 0; d < 2; ++d) {
        pa.whh[0 + d] = rnn_Whh0 + (size_t)d * G_ * H_;
        pa.whh[2 + d] = pr_Whh0  + (size_t)d * G_ * H_;
        pa.whh[4 + d] = rnn_Whh1 + (size_t)d * G_ * H_;
        pa.whh[6 + d] = pr_Whh1  + (size_t)d * G_ * H_;
    }
    int packLanes = 8 * NT_ * KT_ * 64;

    if (ws_size >= N_TOTAL * 4ull) {
        // ================= MFMA-GEMM path =================
        int*   inv   = (int*)d_ws + N_INV;
        unsigned short* wpk = (unsigned short*)(ws + N_WPK);
        unsigned short* bpk = (unsigned short*)(ws + N_BPK);
        float* h_rnn = ws + N_HREG;
        float* h_pr  = h_rnn + 32768ull * 300;
        unsigned short* Uhi = (unsigned short*)h_rnn;              // aliased (dead before scan1 writes)
        unsigned short* Ulo = Uhi + 16384ull * 1024;
        float* X[4];
        for (int i = 0; i < 4; ++i) X[i] = ws + N_X + (size_t)i * 19660800ull;

        k_pos<<<dim3(1), dim3(256), 0, stream>>>(qmask, inv);
        k_pack<<<dim3((packLanes + 255) / 256), dim3(256), 0, stream>>>(pa, wpk);

        // ---- pack layer-0 B fragments (4 combos) ----
        const float* W0p[4] = {rnn_Wih0, rnn_Wih0 + (size_t)G_ * D_,
                               pr_Wih0,  pr_Wih0 + (size_t)G_ * D_};
        const float* b0p[4] = {rnn_b0, rnn_b0 + G_, pr_b0, pr_b0 + G_};
        {
            int lanes = 32 * NTB * 64;
            for (int g = 0; g < 4; ++g)
                k_packB<<<dim3((lanes + 255) / 256), blk, 0, stream>>>(
                    W0p[g], D_, 32, bpk + (size_t)g * BPK0_STR);
        }

        // ---- layer 0 GEMMs, half-M at a time through packed U planes ----
        dim3 gm0(5, 128);
        for (int half = 0; half < 2; ++half) {
            k_packU<<<dim3(8192), blk, 0, stream>>>(U + (size_t)half * 16384 * D_, Uhi, Ulo);
            for (int g = 0; g < 4; ++g)
                k_mgemm<0, 32, 128><<<gm0, blk, 0, stream>>>(
                    Uhi, Ulo, nullptr, bpk + (size_t)g * BPK0_STR, b0p[g],
                    X[g] + (size_t)half * 16384 * G_);
        }

        // ---- layer 0 scan (96 blocks) ----
        ScanArgs sa = z;
        sa.inv = inv;
        setCombo(sa, 0, X[0], wpk, 0, nullptr, h_rnn, B_, 0, 0, 0, 0);
        setCombo(sa, 1, X[1], wpk, 1, nullptr, h_rnn, B_, H_, 1, 0, 0);
        setCombo(sa, 2, X[2], wpk, 2, pr_b0 + 0 * G_, h_pr, BP, 0, 0, 1, 0);
        setCombo(sa, 3, X[3], wpk, 3, pr_b0 + 1 * G_, h_pr, BP, H_, 1, 1, 0);
        sa.blkStart[0] = 0; sa.blkStart[1] = 16; sa.blkStart[2] = 32;
        sa.blkStart[3] = 64; sa.blkStart[4] = 96;
        k_scan<<<dim3(96), sblk, 0, stream>>>(sa);

        // ---- recode h to (hi|lo) in place; pack layer-1 B fragments ----
        k_recode<<<dim3((2457600 + 255) / 256), blk, 0, stream>>>((unsigned int*)h_rnn, 2457600);
        k_recode<<<dim3((4915200 + 255) / 256), blk, 0, stream>>>((unsigned int*)h_pr, 4915200);
        const float* W1p[4] = {rnn_Wih1, rnn_Wih1 + (size_t)G_ * O_,
                               pr_Wih1,  pr_Wih1 + (size_t)G_ * O_};
        {
            int lanes = 10 * NTB * 64;
            for (int g = 0; g < 4; ++g)
                k_packB<<<dim3((lanes + 255) / 256), blk, 0, stream>>>(
                    W1p[g], O_, 10, bpk + (size_t)g * BPK1_STR);
        }

        // ---- layer 1 GEMMs (rnn x2, pr-fwd), rnn scan ----
        dim3 gm1r(5, 256), gm1p(5, 512);
        k_mgemm<1, 10, 300><<<gm1r, blk, 0, stream>>>(
            nullptr, nullptr, (unsigned int*)h_rnn, bpk + 0 * BPK1_STR, rnn_b1 + 0 * G_, X[0]);
        k_mgemm<1, 10, 300><<<gm1r, blk, 0, stream>>>(
            nullptr, nullptr, (unsigned int*)h_rnn, bpk + 1 * BPK1_STR, rnn_b1 + 1 * G_, X[1]);
        k_mgemm<1, 10, 300><<<gm1p, blk, 0, stream>>>(
            nullptr, nullptr, (unsigned int*)h_pr, bpk + 2 * BPK1_STR, pr_b1 + 0 * G_, X[2]);
        ScanArgs sr = z;
        sr.inv = inv;
        setCombo(sr, 0, X[0], wpk, 4, nullptr, h_rnn, B_, 0, 0, 0, 0);
        setCombo(sr, 1, X[1], wpk, 5, nullptr, h_rnn, B_, H_, 1, 0, 0);
        sr.blkStart[0] = 0; sr.blkStart[1] = 16; sr.blkStart[2] = INF;
        sr.blkStart[3] = INF; sr.blkStart[4] = 32;
        k_scan<<<dim3(32), sblk, 0, stream>>>(sr);

        // ---- layer 1 pr-bwd GEMM (into freed X0+X1), fused final scan ----
        k_mgemm<1, 10, 300><<<gm1p, blk, 0, stream>>>(
            nullptr, nullptr, (unsigned int*)h_pr, bpk + 3 * BPK1_STR, pr_b1 + 1 * G_, X[0]);
        ScanArgs sp = z;
        sp.inv = inv; sp.addSrc = h_rnn; sp.umask = umask;
        setCombo(sp, 0, X[2], wpk, 6, nullptr, (float*)d_out, BP, 0, 0, 0, 1);
        setCombo(sp, 1, X[0], wpk, 7, nullptr, (float*)d_out, BP, H_, 1, 0, 1);
        sp.blkStart[0] = 0; sp.blkStart[1] = 32; sp.blkStart[2] = INF;
        sp.blkStart[3] = INF; sp.blkStart[4] = 64;
        k_scan<<<dim3(64), sblk, 0, stream>>>(sp);
        return;
    }

    // ================= legacy small-workspace fallback (fp32 GEMM) =================
    int*   inv   = (int*)d_ws + INV_OFF;
    float* wihT0 = ws + WIHT0_OFF;
    float* wihT1 = ws + WIHT1_OFF;
    unsigned short* wpk = (unsigned short*)(ws + WPK_OFF);
    float* X0    = ws + XW_OFF;
    float* X1    = X0 + XSLOT;
    float* h_rnn = ws + hrnn_off(2);
    float* h_pr  = ws + hpr_off(2);

    const size_t W0S = 1024ull * 600, W1S = 300ull * 600;

    k_pos<<<dim3(1), dim3(256), 0, stream>>>(qmask, inv);
    auto TP = [&](const float* src, float* dst, int K) {
        int total = K * G_;
        k_transpose<<<dim3((total + 255) / 256), dim3(256), 0, stream>>>(src, dst, K);
    };
    for (int d = 0; d < 2; ++d) {
        TP(rnn_Wih0 + (size_t)d * G_ * D_, wihT0 + (0 + d) * W0S, D_);
        TP(pr_Wih0  + (size_t)d * G_ * D_, wihT0 + (2 + d) * W0S, D_);
        TP(rnn_Wih1 + (size_t)d * G_ * O_, wihT1 + (0 + d) * W1S, O_);
        TP(pr_Wih1  + (size_t)d * G_ * O_, wihT1 + (2 + d) * W1S, O_);
    }
    k_pack<<<dim3((packLanes + 255) / 256), dim3(256), 0, stream>>>(pa, wpk);

    dim3 g32k(10, 256), g64k(10, 512);
    for (int d = 0; d < 2; ++d) {
        k_gemm<<<g32k, blk, 0, stream>>>(U, wihT0 + (0 + d) * W0S, rnn_b0 + d * G_, X0, 32768, D_);
        k_gemm<<<g32k, blk, 0, stream>>>(U, wihT0 + (2 + d) * W0S, pr_b0 + d * G_, X1, 32768, D_);
        ScanArgs sa = z;
        sa.inv = inv;
        setCombo(sa, 0, X0, wpk, 0 + d, nullptr, h_rnn, B_, d * H_, d, 0, 0);
        setCombo(sa, 1, X1, wpk, 2 + d, pr_b0 + d * G_, h_pr, BP, d * H_, d, 1, 0);
        sa.blkStart[0] = 0; sa.blkStart[1] = 16; sa.blkStart[2] = INF;
        sa.blkStart[3] = INF; sa.blkStart[4] = 48;
        k_scan<<<dim3(48), sblk, 0, stream>>>(sa);
    }
    k_gemm<<<g32k, blk, 0, stream>>>(h_rnn, wihT1 + 0 * W1S, rnn_b1 + 0 * G_, X0, 32768, O_);
    k_gemm<<<g32k, blk, 0, stream>>>(h_rnn, wihT1 + 1 * W1S, rnn_b1 + 1 * G_, X1, 32768, O_);
    {
        ScanArgs sr = z;
        sr.inv = inv;
        setCombo(sr, 0, X0, wpk, 4, nullptr, h_rnn, B_, 0, 0, 0, 0);
        setCombo(sr, 1, X1, wpk, 5, nullptr, h_rnn, B_, H_, 1, 0, 0);
        sr.blkStart[0] = 0; sr.blkStart[1] = 16; sr.blkStart[2] = INF;
        sr.blkStart[3] = INF; sr.blkStart[4] = 32;
        k_scan<<<dim3(32), sblk, 0, stream>>>(sr);
    }
    for (int d = 0; d < 2; ++d) {
        k_gemm<<<g64k, blk, 0, stream>>>(h_pr, wihT1 + (2 + d) * W1S, pr_b1 + d * G_, X0, 65536, O_);
        ScanArgs sp = z;
        sp.inv = inv; sp.addSrc = h_rnn; sp.umask = umask;
        setCombo(sp, 0, X0, wpk, 6 + d, nullptr, (float*)d_out, BP, d * H_, d, 0, 1);
        sp.blkStart[0] = 0; sp.blkStart[1] = INF; sp.blkStart[2] = INF;
        sp.blkStart[3] = INF; sp.blkStart[4] = 32;
        k_scan<<<dim3(32), sblk, 0, stream>>>(sp);
    }
}